// Round 11
// baseline (183.512 us; speedup 1.0000x reference)
//
#include <hip/hip_runtime.h>
#include <hip/hip_bf16.h>

namespace {
constexpr int DIMC = 768;
constexpr int NH   = 12;
constexpr int HD   = 64;
constexpr int BB   = 2;
constexpr int TT   = 2048;
constexpr int MROWS = BB * TT;                       // 4096
constexpr int NT   = TT / 64;                        // 32 q-tiles
constexpr size_t HEADSZ = (size_t)BB * NH * TT * HD; // 3,145,728
constexpr size_t XSZ    = (size_t)MROWS * DIMC;      // 3,145,728
constexpr size_t WSZ    = (size_t)DIMC * DIMC;       // 589,824
}

using bf16x8 = __attribute__((ext_vector_type(8))) short;
using f32x4  = __attribute__((ext_vector_type(4))) float;

__device__ __forceinline__ f32x4 mfma16(bf16x8 a, bf16x8 b, f32x4 c) {
    return __builtin_amdgcn_mfma_f32_16x16x32_bf16(a, b, c, 0, 0, 0);
}

__device__ __forceinline__ unsigned short f2bf(float f) {
    __hip_bfloat16 h = __float2bfloat16(f);
    return *reinterpret_cast<unsigned short*>(&h);
}

__device__ __forceinline__ void stage16(const void* g, void* l) {
    __builtin_amdgcn_global_load_lds(
        (const __attribute__((address_space(1))) unsigned int*)g,
        (__attribute__((address_space(3))) unsigned int*)l, 16, 0, 0);
}

__device__ __forceinline__ bf16x8 pack8(uint2 lo, uint2 hi) {
    union { unsigned int u[4]; bf16x8 v; } t;
    t.u[0] = lo.x; t.u[1] = lo.y; t.u[2] = hi.x; t.u[3] = hi.y;
    return t.v;
}

// read 8 bytes (4 bf16) from a 64-col bf16 LDS tile at [row][bytecol], chunk-XOR-swizzled
__device__ __forceinline__ uint2 ld64sw(const unsigned short* base, int row, int bytecol) {
    const int chunk  = bytecol >> 4;
    const int within = bytecol & 15;
    const int addr   = row * 128 + (((chunk ^ (row & 7)) << 4) | within);
    return *reinterpret_cast<const uint2*>(reinterpret_cast<const char*>(base) + addr);
}

// ---------------------------------------------------------------------------
// fp32 -> bf16 conversion for x and the 4 weight matrices (one launch).
// ---------------------------------------------------------------------------
__global__ __launch_bounds__(256)
void cvt_kernel(const float* __restrict__ x,  const float* __restrict__ wq,
                const float* __restrict__ wk, const float* __restrict__ wv,
                const float* __restrict__ wo,
                unsigned short* __restrict__ xb,  unsigned short* __restrict__ wqb,
                unsigned short* __restrict__ wkb, unsigned short* __restrict__ wvb,
                unsigned short* __restrict__ wob)
{
    constexpr int NX4 = (int)(XSZ / 4);      // 786432
    constexpr int NW4 = (int)(WSZ / 4);      // 147456
    constexpr int TOT = NX4 + 4 * NW4;       // 1376256
    for (int i = blockIdx.x * blockDim.x + threadIdx.x; i < TOT; i += gridDim.x * blockDim.x) {
        const float* s; unsigned short* d; int off;
        if (i < NX4) { s = x; d = xb; off = i; }
        else {
            const int j  = i - NX4;
            const int ws = j / NW4;
            off = j - ws * NW4;
            s = (ws == 0) ? wq : (ws == 1) ? wk : (ws == 2) ? wv : wo;
            d = (ws == 0) ? wqb : (ws == 1) ? wkb : (ws == 2) ? wvb : wob;
        }
        const float4 f = reinterpret_cast<const float4*>(s)[off];
        ushort4 u;
        u.x = f2bf(f.x); u.y = f2bf(f.y); u.z = f2bf(f.z); u.w = f2bf(f.w);
        reinterpret_cast<ushort4*>(d)[off] = u;
    }
}

// ---------------------------------------------------------------------------
// Unified bf16 MFMA GEMM, D = A @ B^T over K=768. Round 10: triple-buffered
// K-pipeline with COUNTED vmcnt (T3+T4 minimum form). Raw s_barrier (no
// implicit drain) + "s_waitcnt vmcnt(6)": tile t+1's 6 staging loads complete
// while tile t+2's 6 stay in flight across the barrier. Fix for measured
// MfmaUtil 11.4% / 46.6us (2-phase drain stall, m233 signature).
// Tile 128(A)x64(B); LDS 72KB -> 2 blocks/CU. 4 waves: 2(A) x 2(B), acc[4][2].
// Modes: 0/1 = q/k RoPE -> (B,H,T,D) bf16 (q pre-scaled 0.125);
// 2 = v -> (B,H,D,T) bf16; 3 = out-proj fp32.
// ---------------------------------------------------------------------------
__global__ __launch_bounds__(256)
void gemm768_kernel(int modeBase,
                    const unsigned short* __restrict__ xb,
                    const unsigned short* __restrict__ wqb,
                    const unsigned short* __restrict__ wkb,
                    const unsigned short* __restrict__ wvb,
                    const unsigned short* __restrict__ wob,
                    const unsigned short* __restrict__ ybf,
                    const float* __restrict__ cosT,
                    const float* __restrict__ sinT,
                    unsigned short* __restrict__ qo,
                    unsigned short* __restrict__ ko,
                    unsigned short* __restrict__ vto,
                    float* __restrict__ outp)
{
    const int mode = modeBase + blockIdx.z;
    const unsigned short* __restrict__ A  = (mode == 0) ? wqb : (mode == 1) ? wkb
                                          : (mode == 2) ? wvb : ybf;
    const unsigned short* __restrict__ Bp = (mode == 3) ? wob : xb;

    const int tid  = threadIdx.x;
    const int w    = tid >> 6;
    const int lane = tid & 63;
    const int l15  = lane & 15;
    const int g    = lane >> 4;
    const int rA0  = blockIdx.x * 128;
    const int rB0  = blockIdx.y * 64;
    const int wa0  = (w & 1) * 64;     // wave offset in A rows
    const int wb0  = (w >> 1) * 32;    // wave offset in B rows

    __shared__ __align__(16) unsigned short At[3][128 * 64];
    __shared__ __align__(16) unsigned short Bt[3][64 * 64];

    // stage a (rows x 64) bf16 tile (ld = 768 elems) into LDS, row-chunk swizzled
    // per-wave cost: stageA = 4 vmem instrs, stageB = 2 vmem instrs (6/tile total)
    auto stageA = [&](unsigned short* lds, const unsigned short* gRowBase) {
        const char* gb = reinterpret_cast<const char*>(gRowBase);
        char* lb = reinterpret_cast<char*>(lds);
        #pragma unroll
        for (int it = 0; it < 4; ++it) {      // 128 rows * 8 chunks = 1024
            const int ci  = it * 256 + tid;
            const int row = ci >> 3, cp = ci & 7;
            stage16(gb + (size_t)row * 1536 + ((cp ^ (row & 7)) << 4),
                    lb + (it * 256 + w * 64) * 16);
        }
    };
    auto stageB = [&](unsigned short* lds, const unsigned short* gRowBase) {
        const char* gb = reinterpret_cast<const char*>(gRowBase);
        char* lb = reinterpret_cast<char*>(lds);
        #pragma unroll
        for (int it = 0; it < 2; ++it) {      // 64 rows * 8 chunks = 512
            const int ci  = it * 256 + tid;
            const int row = ci >> 3, cp = ci & 7;
            stage16(gb + (size_t)row * 1536 + ((cp ^ (row & 7)) << 4),
                    lb + (it * 256 + w * 64) * 16);
        }
    };

    f32x4 acc[4][2];
    #pragma unroll
    for (int mf = 0; mf < 4; ++mf)
        #pragma unroll
        for (int nf = 0; nf < 2; ++nf) acc[mf][nf] = f32x4{0.f, 0.f, 0.f, 0.f};

    // prologue: prefetch tiles 0 and 1 (12 vmem instrs in flight)
    stageA(At[0], A  + (size_t)rA0 * DIMC);
    stageB(Bt[0], Bp + (size_t)rB0 * DIMC);
    stageA(At[1], A  + (size_t)rA0 * DIMC + 64);
    stageB(Bt[1], Bp + (size_t)rB0 * DIMC + 64);
    asm volatile("s_waitcnt vmcnt(6)" ::: "memory");   // tile 0 complete; tile 1 in flight
    __builtin_amdgcn_s_barrier();

    for (int kt = 0; kt < 12; ++kt) {
        const int cur = kt % 3;
        if (kt + 2 < 12) {
            const int nxt = (kt + 2) % 3;    // buffer last read at iter kt-1; barrier'd
            stageA(At[nxt], A  + (size_t)rA0 * DIMC + (kt + 2) * 64);
            stageB(Bt[nxt], Bp + (size_t)rB0 * DIMC + (kt + 2) * 64);
        }
        #pragma unroll
        for (int ks = 0; ks < 2; ++ks) {
            bf16x8 af[4], bfr[2];
            #pragma unroll
            for (int mf = 0; mf < 4; ++mf)
                af[mf] = pack8(ld64sw(At[cur], wa0 + mf*16 + l15, ks*64 + g*8),
                               ld64sw(At[cur], wa0 + mf*16 + l15, ks*64 + 32 + g*8));
            #pragma unroll
            for (int nf = 0; nf < 2; ++nf)
                bfr[nf] = pack8(ld64sw(Bt[cur], wb0 + nf*16 + l15, ks*64 + g*8),
                                ld64sw(Bt[cur], wb0 + nf*16 + l15, ks*64 + 32 + g*8));
            #pragma unroll
            for (int mf = 0; mf < 4; ++mf)
                #pragma unroll
                for (int nf = 0; nf < 2; ++nf)
                    acc[mf][nf] = mfma16(af[mf], bfr[nf], acc[mf][nf]);
        }
        if (kt < 11) {
            // tile kt+1 must be complete before next iter reads it; keep tile
            // kt+2's 6 loads in flight (counted wait, never drain mid-loop).
            if (kt + 2 < 12) asm volatile("s_waitcnt vmcnt(6)" ::: "memory");
            else             asm volatile("s_waitcnt vmcnt(0)" ::: "memory");
            __builtin_amdgcn_s_barrier();
        }
    }

    if (mode <= 1) {
        // RoPE + store bf16 (B,H,T,D); q additionally pre-scaled by 1/sqrt(64)
        unsigned short* __restrict__ o = (mode == 0) ? qo : ko;
        const float qs = (mode == 0) ? 0.125f : 1.0f;
        #pragma unroll
        for (int mf = 0; mf < 4; ++mf) {
            const int ra0 = rA0 + wa0 + mf * 16 + g * 4;     // n at r=0
            const int h   = ra0 >> 6;
            const int d0  = ra0 & 63;                        // multiple of 4
            #pragma unroll
            for (int nf = 0; nf < 2; ++nf) {
                const int rb = rB0 + wb0 + nf * 16 + l15;    // m
                const int b  = rb >> 11;
                const int t  = rb & (TT - 1);
                const float c0 = cosT[(size_t)t * HD + d0];
                const float s0 = sinT[(size_t)t * HD + d0];
                const float c2 = cosT[(size_t)t * HD + d0 + 2];
                const float s2 = sinT[(size_t)t * HD + d0 + 2];
                const float v0 = acc[mf][nf][0], v1 = acc[mf][nf][1];
                const float v2 = acc[mf][nf][2], v3 = acc[mf][nf][3];
                ushort4 u;
                u.x = f2bf((v0 * c0 - v1 * s0) * qs);
                u.y = f2bf((v1 * c0 + v0 * s0) * qs);
                u.z = f2bf((v2 * c2 - v3 * s2) * qs);
                u.w = f2bf((v3 * c2 + v2 * s2) * qs);
                *reinterpret_cast<ushort4*>(&o[(((size_t)b * NH + h) * TT + t) * HD + d0]) = u;
            }
        }
    } else if (mode == 2) {
        // V^T store bf16 (B,H,D,T): vt[(b*768 + n)*T + t]
        #pragma unroll
        for (int mf = 0; mf < 4; ++mf)
            #pragma unroll
            for (int nf = 0; nf < 2; ++nf) {
                const int rb = rB0 + wb0 + nf * 16 + l15;    // m
                const int b  = rb >> 11;
                const int t  = rb & (TT - 1);
                #pragma unroll
                for (int r = 0; r < 4; ++r) {
                    const int n = rA0 + wa0 + mf * 16 + g * 4 + r;
                    vto[((size_t)b * DIMC + n) * TT + t] = f2bf(acc[mf][nf][r]);
                }
            }
    } else {
        // out-proj fp32: A rows = m, B rows = n
        #pragma unroll
        for (int mf = 0; mf < 4; ++mf)
            #pragma unroll
            for (int nf = 0; nf < 2; ++nf) {
                const int n = rB0 + wb0 + nf * 16 + l15;
                #pragma unroll
                for (int r = 0; r < 4; ++r) {
                    const int m = rA0 + wa0 + mf * 16 + g * 4 + r;
                    outp[(size_t)m * DIMC + n] = acc[mf][nf][r];
                }
            }
    }
}

// ---------------------------------------------------------------------------
// MFMA flash attention (validated round 6): XCD-aware grid + fixed-m softmax.
// ---------------------------------------------------------------------------
__global__ __launch_bounds__(256)
void attn_mfma_kernel(const unsigned short* __restrict__ qg,   // (B,H,T,D) bf16, pre-scaled
                      const unsigned short* __restrict__ kg,   // (B,H,T,D) bf16
                      const unsigned short* __restrict__ vg,   // (B,H,D,T) bf16
                      unsigned short* __restrict__ y)          // (B,T,C) bf16
{
    // id%8 = XCD (empirical round-robin); give each XCD 3 full heads.
    const int id   = blockIdx.x;               // 0..383
    const int j    = id >> 3;                  // 0..47
    const int bh   = (id & 7) + 8 * (j % 3);   // 0..23
    const int pair = j / 3;                    // 0..15
    const int b    = bh / NH;
    const int h    = bh % NH;
    const int tid  = threadIdx.x;
    const int w    = tid >> 6;
    const int lane = tid & 63;
    const int l15  = lane & 15;
    const int g    = lane >> 4;

    __shared__ __align__(16) unsigned short Ks[2][4096];
    __shared__ __align__(16) unsigned short Vs[2][4096];       // V^T tile: [d][kv]

    const unsigned short* kbase = kg + (size_t)bh * TT * HD;
    const unsigned short* vbase = vg + (size_t)bh * HD * TT;

    auto stageK = [&](int buf, int kt) {
        const char* gb = reinterpret_cast<const char*>(kbase + (size_t)kt * 64 * HD);
        #pragma unroll
        for (int it = 0; it < 2; ++it) {
            const int ci  = it * 256 + tid;
            const int row = ci >> 3, cp = ci & 7;
            stage16(gb + row * 128 + ((cp ^ (row & 7)) << 4),
                    reinterpret_cast<char*>(&Ks[buf][0]) + (it * 256 + w * 64) * 16);
        }
    };
    auto stageV = [&](int buf, int kt) {
        const char* gb = reinterpret_cast<const char*>(vbase + (size_t)kt * 64);
        #pragma unroll
        for (int it = 0; it < 2; ++it) {
            const int ci  = it * 256 + tid;
            const int row = ci >> 3, cp = ci & 7;
            stage16(gb + (size_t)row * (TT * 2) + ((cp ^ (row & 7)) << 4),
                    reinterpret_cast<char*>(&Vs[buf][0]) + (it * 256 + w * 64) * 16);
        }
    };

    #pragma unroll 1
    for (int hf = 0; hf < 2; ++hf) {
        const int qt  = hf ? (NT - 1 - pair) : pair;
        const int nkt = qt + 1;
        const int qloc = w * 16 + l15;

        const unsigned short* qrow = qg + ((size_t)bh * TT + (size_t)qt * 64 + qloc) * HD;
        bf16x8 qf[2];
        #pragma unroll
        for (int ks = 0; ks < 2; ++ks) {
            uint2 lo = *reinterpret_cast<const uint2*>(qrow + ks * 32 + g * 4);
            uint2 hi = *reinterpret_cast<const uint2*>(qrow + ks * 32 + 16 + g * 4);
            qf[ks] = pack8(lo, hi);
        }

        f32x4 oacc[4];
        #pragma unroll
        for (int nf = 0; nf < 4; ++nf) oacc[nf] = f32x4{0.f, 0.f, 0.f, 0.f};
        float lsum = 0.f;

        stageK(0, 0);
        stageV(0, 0);
        __syncthreads();

        for (int kt = 0; kt < nkt; ++kt) {
            const int buf = kt & 1;
            if (kt + 1 < nkt) { stageK(buf ^ 1, kt + 1); stageV(buf ^ 1, kt + 1); }

            // S^T = K @ Q^T (Q pre-scaled by 1/sqrt(64))
            f32x4 sacc[4];
            #pragma unroll
            for (int mf = 0; mf < 4; ++mf) sacc[mf] = f32x4{0.f, 0.f, 0.f, 0.f};
            #pragma unroll
            for (int mf = 0; mf < 4; ++mf) {
                #pragma unroll
                for (int ks = 0; ks < 2; ++ks) {
                    bf16x8 kf = pack8(ld64sw(Ks[buf], mf*16 + l15, ks*64 + g*8),
                                      ld64sw(Ks[buf], mf*16 + l15, ks*64 + 32 + g*8));
                    sacc[mf] = mfma16(kf, qf[ks], sacc[mf]);
                }
            }

            // fixed-m softmax: P = exp(S), masked entries -> 0; l accumulates per-lane
            float ev[4][4];
            const bool diag = (kt == qt);
            #pragma unroll
            for (int mf = 0; mf < 4; ++mf)
                #pragma unroll
                for (int r = 0; r < 4; ++r) {
                    float e = __expf(sacc[mf][r]);
                    if (diag && (mf*16 + 4*g + r) > qloc) e = 0.f;
                    ev[mf][r] = e;
                    lsum += e;
                }

            bf16x8 pf[2];
            #pragma unroll
            for (int ks = 0; ks < 2; ++ks) {
                union { unsigned short s[8]; bf16x8 v; } t;
                #pragma unroll
                for (int jj = 0; jj < 4; ++jj) {
                    t.s[jj]     = f2bf(ev[2*ks][jj]);
                    t.s[4 + jj] = f2bf(ev[2*ks + 1][jj]);
                }
                pf[ks] = t.v;
            }

            #pragma unroll
            for (int nf = 0; nf < 4; ++nf) {
                #pragma unroll
                for (int ks = 0; ks < 2; ++ks) {
                    bf16x8 vf = pack8(ld64sw(Vs[buf], nf*16 + l15, ks*64 + g*8),
                                      ld64sw(Vs[buf], nf*16 + l15, ks*64 + 32 + g*8));
                    oacc[nf] = mfma16(pf[ks], vf, oacc[nf]);
                }
            }
            __syncthreads();
        }

        // row sum across the 4 lane-groups, then normalize + store
        lsum += __shfl_xor(lsum, 16, 64);
        lsum += __shfl_xor(lsum, 32, 64);
        const float inv = 1.0f / lsum;
        float ir[4];
        #pragma unroll
        for (int r = 0; r < 4; ++r) ir[r] = __shfl(inv, 4*g + r, 64);
        #pragma unroll
        for (int nf = 0; nf < 4; ++nf)
            #pragma unroll
            for (int r = 0; r < 4; ++r) {
                const int t = qt*64 + w*16 + 4*g + r;
                y[((size_t)b * TT + t) * DIMC + h*64 + nf*16 + l15] = f2bf(oacc[nf][r] * ir[r]);
            }
    }
}

// ---------------------------------------------------------------------------
extern "C" void kernel_launch(void* const* d_in, const int* in_sizes, int n_in,
                              void* d_out, int out_size, void* d_ws, size_t ws_size,
                              hipStream_t stream)
{
    (void)in_sizes; (void)n_in; (void)out_size; (void)ws_size;

    const float* x    = (const float*)d_in[0];
    const float* wq   = (const float*)d_in[1];
    const float* wk   = (const float*)d_in[2];
    const float* wv   = (const float*)d_in[3];
    const float* wo   = (const float*)d_in[4];
    const float* cosT = (const float*)d_in[5];
    const float* sinT = (const float*)d_in[6];
    float* out = (float*)d_out;

    unsigned short* xb  = (unsigned short*)d_ws;     // bf16 x            (B*T, C)
    unsigned short* wqb = xb  + XSZ;                 // bf16 weights
    unsigned short* wkb = wqb + WSZ;
    unsigned short* wvb = wkb + WSZ;
    unsigned short* wob = wvb + WSZ;
    unsigned short* qb  = wob + WSZ;                 // (B,H,T,D) bf16 (pre-scaled)
    unsigned short* kb  = qb  + HEADSZ;              // (B,H,T,D) bf16
    unsigned short* vt  = kb  + HEADSZ;              // (B,H,D,T) bf16
    unsigned short* yb  = vt  + HEADSZ;              // (B,T,C)  bf16
    // ws use: ~36.2 MB

    cvt_kernel<<<2048, 256, 0, stream>>>(x, wq, wk, wv, wo, xb, wqb, wkb, wvb, wob);
    gemm768_kernel<<<dim3(6, 64, 3), 256, 0, stream>>>(0, xb, wqb, wkb, wvb, wob, yb,
                                                       cosT, sinT, qb, kb, vt, nullptr);
    attn_mfma_kernel<<<dim3(16 * 24), 256, 0, stream>>>(qb, kb, vt, yb);
    gemm768_kernel<<<dim3(32, 12, 1), 256, 0, stream>>>(3, xb, wqb, wkb, wvb, wob, yb,
                                                        cosT, sinT, qb, kb, vt, out);
}